// Round 3
// baseline (541.359 us; speedup 1.0000x reference)
//
#include <hip/hip_runtime.h>

#define E_TOT   300000
#define DN      128
#define DOUT    128
#define XP      392   // X row stride in shorts: 784B = 16B-aligned, 2-way (free) banks

typedef float  f32x4  __attribute__((ext_vector_type(4)));
typedef __bf16 bf16x8 __attribute__((ext_vector_type(8)));
typedef unsigned int u32;

__device__ __forceinline__ unsigned short f2bf(float f) {
    union { float f; unsigned int u; } v; v.f = f;
    return (unsigned short)((v.u + 0x7FFFu + ((v.u >> 16) & 1u)) >> 16);
}

// Repack W1 [384][256] -> bf16 [6][256][64]  (chunk, n, k)  and
//        W2 [256][128] -> bf16 [4][128][64]
__global__ void prep_weights(const float* __restrict__ W1,
                             const float* __restrict__ W2,
                             unsigned short* __restrict__ W1p,
                             unsigned short* __restrict__ W2p) {
    int t = blockIdx.x * 256 + threadIdx.x;
    if (t < 384 * 256) {
        int k = t >> 8, n = t & 255;
        W1p[(((k >> 6) << 8) + n) * 64 + (k & 63)] = f2bf(W1[t]);
    } else {
        int t2 = t - 384 * 256;
        int k = t2 >> 7, n = t2 & 127;
        W2p[(((k >> 6) << 7) + n) * 64 + (k & 63)] = f2bf(W2[t2]);
    }
}

__global__ __launch_bounds__(256, 3) void edge_mlp(
    const float* __restrict__ node_attr,
    const float* __restrict__ edge_attr,
    const int*   __restrict__ eidx,
    const unsigned short* __restrict__ W1p,
    const unsigned short* __restrict__ W2p,
    const float* __restrict__ b1,
    const float* __restrict__ b2,
    const float* __restrict__ ln_g,
    const float* __restrict__ ln_b,
    float* __restrict__ out)
{
    // One LDS region, two lives separated by barriers:
    //   life 1: full X block, bf16 [64][XP]  (50176 B)
    //   life 2: h exchange,  bf16 [64][264]  (33792 B)
    __shared__ __align__(16) unsigned short smem[64 * XP];
    unsigned short* Xb   = smem;
    unsigned short* hbuf = smem;

    const int tid  = threadIdx.x;
    const int wid  = tid >> 6;
    const int lane = tid & 63;
    const int quad = lane >> 4;
    const int l16  = lane & 15;
    const int eb   = blockIdx.x * 64;

    // staging geometry: 16 threads per row, thread covers rows r0+16i
    const int r0 = tid >> 4;
    const int q4 = tid & 15;

    u32 sOff[4], rOff[4], eOff[4];
    #pragma unroll
    for (int i = 0; i < 4; ++i) {
        int e = eb + r0 + (i << 4);
        if (e >= E_TOT) e = E_TOT - 1;
        sOff[i] = (u32)eidx[e] * (DN * 4);
        rOff[i] = (u32)eidx[E_TOT + e] * (DN * 4);
        eOff[i] = (u32)e * (DN * 4);
    }

    f32x4 acc[4][4];
    #pragma unroll
    for (int i = 0; i < 4; ++i)
        #pragma unroll
        for (int j = 0; j < 4; ++j)
            acc[i][j] = (f32x4){0.f, 0.f, 0.f, 0.f};

    // ---------- Stage FULL X[64x384] once (the only gather phase) ----------
    // X col layout: [sender 0..127 | receiver 128..255 | edge 256..383]
    #pragma unroll
    for (int i = 0; i < 4; ++i) {
        const int row = r0 + (i << 4);
        const float* sp = (const float*)((const char*)node_attr + sOff[i]);
        const float* rp = (const float*)((const char*)node_attr + rOff[i]);
        const float* ep = (const float*)((const char*)edge_attr + eOff[i]);
        float4 v[6];
        v[0] = *(const float4*)(sp + (q4 << 2));
        v[1] = *(const float4*)(sp + 64 + (q4 << 2));
        v[2] = *(const float4*)(rp + (q4 << 2));
        v[3] = *(const float4*)(rp + 64 + (q4 << 2));
        v[4] = *(const float4*)(ep + (q4 << 2));
        v[5] = *(const float4*)(ep + 64 + (q4 << 2));
        #pragma unroll
        for (int s = 0; s < 6; ++s) {
            ushort4 p;
            p.x = f2bf(v[s].x); p.y = f2bf(v[s].y);
            p.z = f2bf(v[s].z); p.w = f2bf(v[s].w);
            *(ushort4*)(Xb + row * XP + (s << 6) + (q4 << 2)) = p;
        }
    }
    __syncthreads();   // barrier 1: X ready; no further gathers exist

    // ---------- Layer 1: X[64x384] @ W1[384x256], ZERO barriers ----------
    // B-fragments straight from L2-resident W1p (n,k layout: 16 fully-used
    // 64B lines per load). No scattered loads outstanding anywhere in this
    // loop, so vmcnt waits cover only uniform ~L2-latency W-loads, which
    // pipeline across unrolled iterations and co-resident waves.
    #pragma unroll 2
    for (int c = 0; c < 6; ++c) {
        const unsigned short* wbase = W1p + (((c << 8) + (wid << 6)) << 6);
        bf16x8 bfr[2][4];
        #pragma unroll
        for (int ks = 0; ks < 2; ++ks)
            #pragma unroll
            for (int nt = 0; nt < 4; ++nt)
                bfr[ks][nt] = *(const bf16x8*)(wbase + (((nt << 4) + l16) << 6) + (ks << 5) + (quad << 3));
        #pragma unroll
        for (int ks = 0; ks < 2; ++ks) {
            bf16x8 a[4];
            #pragma unroll
            for (int mt = 0; mt < 4; ++mt)
                a[mt] = *(const bf16x8*)(Xb + ((mt << 4) + l16) * XP + (c << 6) + (ks << 5) + (quad << 3));
            #pragma unroll
            for (int nt = 0; nt < 4; ++nt)
                #pragma unroll
                for (int mt = 0; mt < 4; ++mt)
                    acc[mt][nt] = __builtin_amdgcn_mfma_f32_16x16x32_bf16(a[mt], bfr[ks][nt], acc[mt][nt], 0, 0, 0);
        }
    }

    __syncthreads();   // barrier 2: all X reads done -> smem becomes hbuf

    // bias + ReLU -> hbuf
    float b1v[4];
    #pragma unroll
    for (int nt = 0; nt < 4; ++nt) b1v[nt] = b1[(wid << 6) + (nt << 4) + l16];
    #pragma unroll
    for (int mt = 0; mt < 4; ++mt)
        #pragma unroll
        for (int nt = 0; nt < 4; ++nt)
            #pragma unroll
            for (int r = 0; r < 4; ++r) {
                int row = (mt << 4) + (quad << 2) + r;
                int col = (wid << 6) + (nt << 4) + l16;
                float v = acc[mt][nt][r] + b1v[nt];
                hbuf[row * 264 + col] = f2bf(v > 0.f ? v : 0.f);
            }
    __syncthreads();   // barrier 3: h ready

    // ---------- Layer 2: h[64x256] @ W2[256x128], B direct from L2 ----------
    f32x4 acc2[8];
    #pragma unroll
    for (int nt = 0; nt < 8; ++nt) acc2[nt] = (f32x4){0.f, 0.f, 0.f, 0.f};

    #pragma unroll 2
    for (int c2 = 0; c2 < 4; ++c2) {
        const unsigned short* w2base = W2p + (c2 << 13);
        #pragma unroll
        for (int ks = 0; ks < 2; ++ks) {
            bf16x8 b2f[8];
            #pragma unroll
            for (int nt = 0; nt < 8; ++nt)
                b2f[nt] = *(const bf16x8*)(w2base + (((nt << 4) + l16) << 6) + (ks << 5) + (quad << 3));
            bf16x8 a = *(const bf16x8*)(hbuf + ((wid << 4) + l16) * 264 + (c2 << 6) + (ks << 5) + (quad << 3));
            #pragma unroll
            for (int nt = 0; nt < 8; ++nt)
                acc2[nt] = __builtin_amdgcn_mfma_f32_16x16x32_bf16(a, b2f[nt], acc2[nt], 0, 0, 0);
        }
    }

    // ---------- bias + LayerNorm (in-register, 16-lane shuffle) ----------
    float b2v[8], gv[8], bev[8];
    #pragma unroll
    for (int nt = 0; nt < 8; ++nt) {
        int n = (nt << 4) + l16;
        b2v[nt] = b2[n]; gv[nt] = ln_g[n]; bev[nt] = ln_b[n];
    }
    #pragma unroll
    for (int r = 0; r < 4; ++r) {
        int e = eb + (wid << 4) + (quad << 2) + r;
        float x[8];
        float s = 0.f, s2 = 0.f;
        #pragma unroll
        for (int nt = 0; nt < 8; ++nt) {
            x[nt] = acc2[nt][r] + b2v[nt];
            s += x[nt]; s2 += x[nt] * x[nt];
        }
        #pragma unroll
        for (int m = 1; m < 16; m <<= 1) {
            s  += __shfl_xor(s, m, 64);
            s2 += __shfl_xor(s2, m, 64);
        }
        const float mu  = s * (1.f / 128.f);
        const float var = s2 * (1.f / 128.f) - mu * mu;
        const float rs  = rsqrtf(var + 1e-5f);
        if (e < E_TOT) {
            float* orow = out + (size_t)e * DOUT;
            #pragma unroll
            for (int nt = 0; nt < 8; ++nt)
                orow[(nt << 4) + l16] = (x[nt] - mu) * rs * gv[nt] + bev[nt];
        }
    }
}

extern "C" void kernel_launch(void* const* d_in, const int* in_sizes, int n_in,
                              void* d_out, int out_size, void* d_ws, size_t ws_size,
                              hipStream_t stream) {
    const float* node_attr = (const float*)d_in[0];
    const float* edge_attr = (const float*)d_in[1];
    const int*   eidx      = (const int*)d_in[2];
    const float* W1        = (const float*)d_in[3];
    const float* b1        = (const float*)d_in[4];
    const float* W2        = (const float*)d_in[5];
    const float* b2        = (const float*)d_in[6];
    const float* ln_g      = (const float*)d_in[7];
    const float* ln_b      = (const float*)d_in[8];

    unsigned short* W1p = (unsigned short*)d_ws;          // 98304 bf16
    unsigned short* W2p = W1p + 384 * 256;                // 32768 bf16

    prep_weights<<<512, 256, 0, stream>>>(W1, W2, W1p, W2p);

    const int nblocks = (E_TOT + 63) / 64;                // 4688
    edge_mlp<<<nblocks, 256, 0, stream>>>(node_attr, edge_attr, eidx,
                                          W1p, W2p, b1, b2, ln_g, ln_b,
                                          (float*)d_out);
}